// Round 8
// baseline (530.877 us; speedup 1.0000x reference)
//
#include <hip/hip_runtime.h>

#define DIM 512
#define DIM2 1024
#define NGRAPH 512
#define LN_EPS 1e-5f
#define TPB 256
#define NB 2048   // chunk count for segsum/resid — matched for L3 reuse

typedef float f4 __attribute__((ext_vector_type(4)));

__device__ __forceinline__ void nts(f4* p, f4 v) { __builtin_nontemporal_store(v, p); }

// ---------------------------------------------------------------------------
// K1: segment sums, chunk-contiguous, branchless 16-row inner loop
// (8 independent 16B loads in flight per lane). Cached reads seed L3 for K3.
// ---------------------------------------------------------------------------
__global__ __launch_bounds__(TPB) void segsum_kernel(const f4* __restrict__ x4,
                                                     const int* __restrict__ bi,
                                                     float* __restrict__ sums,
                                                     int n_nodes, int rpb) {
    const int blk = blockIdx.x, t = threadIdx.x;
    const int r0 = blk * rpb;
    const int r1 = min(n_nodes, r0 + rpb);
    if (r0 >= r1) return;
    const int par = t >> 7;      // 256 thr = 2 rows x 128 f4-cols
    const int c = t & 127;

    int cur = r0;
    while (cur < r1) {
        const int g = bi[cur];
        int lo = cur + 1, hi = r1;
        while (lo < hi) {
            int mid = (lo + hi) >> 1;
            if (bi[mid] <= g) lo = mid + 1; else hi = mid;
        }
        const int send = lo;

        f4 a0={0,0,0,0}, a1={0,0,0,0}, a2={0,0,0,0}, a3={0,0,0,0};
        f4 a4={0,0,0,0}, a5={0,0,0,0}, a6={0,0,0,0}, a7={0,0,0,0};
        int r = cur;
        for (; r + 16 <= send; r += 16) {
            const size_t b = (size_t)(r + par) * 128 + c;
            f4 v0 = x4[b];        f4 v1 = x4[b + 256];
            f4 v2 = x4[b + 512];  f4 v3 = x4[b + 768];
            f4 v4 = x4[b + 1024]; f4 v5 = x4[b + 1280];
            f4 v6 = x4[b + 1536]; f4 v7 = x4[b + 1792];
            a0 += v0; a1 += v1; a2 += v2; a3 += v3;
            a4 += v4; a5 += v5; a6 += v6; a7 += v7;
        }
        if (r + 8 <= send) {
            const size_t b = (size_t)(r + par) * 128 + c;
            f4 v0 = x4[b];       f4 v1 = x4[b + 256];
            f4 v2 = x4[b + 512]; f4 v3 = x4[b + 768];
            a0 += v0; a1 += v1; a2 += v2; a3 += v3;
            r += 8;
        }
        for (int rr = r + par; rr < send; rr += 2)
            a0 += x4[(size_t)rr * 128 + c];

        a0 += a1 + a2 + a3 + a4 + a5 + a6 + a7;
        float* d = sums + (size_t)g * DIM + c * 4;
        atomicAdd(d + 0, a0[0]);
        atomicAdd(d + 1, a0[1]);
        atomicAdd(d + 2, a0[2]);
        atomicAdd(d + 3, a0[3]);
        cur = send;
    }
}

// ---------------------------------------------------------------------------
// K2: whole FFN fused. 64 blocks x 512 thr; block owns 8 graph rows.
//   gemm1 (2 cols/thread, mean fold, relu) -> h1 in LDS (32 KB)
//   gemm2 (1 col/thread, f4 LDS broadcast reads) + bias
//   LayerNorm (shuffle + LDS reduce over 8 waves) -> hvn (d_out tail)
// ---------------------------------------------------------------------------
__global__ __launch_bounds__(512) void ffn_kernel(const float* __restrict__ S,
                                                  const int* __restrict__ bi,
                                                  const float* __restrict__ W1,
                                                  const float* __restrict__ b1,
                                                  const float* __restrict__ W2,
                                                  const float* __restrict__ b2,
                                                  const float* __restrict__ gamma,
                                                  const float* __restrict__ beta,
                                                  float* __restrict__ hvn,
                                                  int n_nodes) {
    __shared__ float h1s[8][DIM2];          // 32 KB
    __shared__ int sb[9];
    __shared__ float sh_s[8][8], sh_ss[8][8];
    const int t = threadIdx.x;
    const int r0 = blockIdx.x * 8;

    if (t < 9) {
        int v = r0 + t;
        int lo = 0, hi = n_nodes;
        while (lo < hi) {
            int mid = (lo + hi) >> 1;
            if (bi[mid] < v) lo = mid + 1; else hi = mid;
        }
        sb[t] = lo;
    }
    __syncthreads();
    float inv[8];
#pragma unroll
    for (int r = 0; r < 8; ++r) {
        int cnt = sb[r + 1] - sb[r];
        inv[r] = 1.0f / (float)(cnt > 0 ? cnt : 1);
    }

    // --- gemm1: h1 = relu((S*inv) @ W1 + b1), 2 cols per thread ----------
    const int c0 = t, c1 = t + 512;
    float acc0[8] = {0,0,0,0,0,0,0,0};
    float acc1[8] = {0,0,0,0,0,0,0,0};
#pragma unroll 4
    for (int k = 0; k < DIM; ++k) {
        float w0 = W1[(size_t)k * DIM2 + c0];
        float w1 = W1[(size_t)k * DIM2 + c1];
#pragma unroll
        for (int r = 0; r < 8; ++r) {
            float s = S[(size_t)(r0 + r) * DIM + k];   // block-uniform
            acc0[r] += s * w0;
            acc1[r] += s * w1;
        }
    }
    float bb0 = b1[c0], bb1 = b1[c1];
#pragma unroll
    for (int r = 0; r < 8; ++r) {
        float v0 = acc0[r] * inv[r] + bb0;
        float v1 = acc1[r] * inv[r] + bb1;
        h1s[r][c0] = v0 > 0.0f ? v0 : 0.0f;
        h1s[r][c1] = v1 > 0.0f ? v1 : 0.0f;
    }
    __syncthreads();

    // --- gemm2: acc = h1 @ W2 + b2, 1 col per thread ----------------------
    float acc[8] = {0,0,0,0,0,0,0,0};
#pragma unroll 2
    for (int k4 = 0; k4 < DIM2 / 4; ++k4) {
        float w0 = W2[(size_t)(4 * k4 + 0) * DIM + t];
        float w1 = W2[(size_t)(4 * k4 + 1) * DIM + t];
        float w2v = W2[(size_t)(4 * k4 + 2) * DIM + t];
        float w3 = W2[(size_t)(4 * k4 + 3) * DIM + t];
#pragma unroll
        for (int r = 0; r < 8; ++r) {
            f4 h = *(const f4*)&h1s[r][4 * k4];        // LDS broadcast
            acc[r] += h[0] * w0 + h[1] * w1 + h[2] * w2v + h[3] * w3;
        }
    }
    float bb = b2[t];
    float v[8];
#pragma unroll
    for (int r = 0; r < 8; ++r) v[r] = acc[r] + bb;

    // --- LayerNorm over the 512 cols (8 waves) ----------------------------
    const int wid = t >> 6, lane = t & 63;
#pragma unroll
    for (int r = 0; r < 8; ++r) {
        float s = v[r], ss = v[r] * v[r];
#pragma unroll
        for (int off = 32; off > 0; off >>= 1) {
            s  += __shfl_xor(s,  off);
            ss += __shfl_xor(ss, off);
        }
        if (lane == 0) { sh_s[r][wid] = s; sh_ss[r][wid] = ss; }
    }
    __syncthreads();
    float gm = gamma[t], bt = beta[t];
#pragma unroll
    for (int r = 0; r < 8; ++r) {
        float s = 0.f, ss = 0.f;
#pragma unroll
        for (int w = 0; w < 8; ++w) { s += sh_s[r][w]; ss += sh_ss[r][w]; }
        float mu  = s * (1.0f / DIM);
        float var = ss * (1.0f / DIM) - mu * mu;
        float rs  = rsqrtf(var + LN_EPS);
        hvn[(size_t)(r0 + r) * DIM + t] = (v[r] - mu) * rs * gm + bt;
    }
}

// ---------------------------------------------------------------------------
// K3: x_new = x + hvn[batch_idx]. Same chunk partition as K1, reverse
// macro-order (L3-hot tail first). 16 independent cached x loads in flight
// per lane; NT stores.
// ---------------------------------------------------------------------------
__global__ __launch_bounds__(TPB) void resid_kernel(const f4* __restrict__ x4,
                                                    const int* __restrict__ bi,
                                                    const f4* __restrict__ hv4,
                                                    f4* __restrict__ out4,
                                                    int n_nodes, int rpb) {
    const int blk = blockIdx.x, t = threadIdx.x;
    const int r0 = blk * rpb;
    const int r1 = min(n_nodes, r0 + rpb);
    if (r0 >= r1) return;
    const int base = r0 * 128, endi = r1 * 128;
    const int gsz = TPB * 16;
    const int ngrp = (endi - base + gsz - 1) / gsz;

    for (int gi = ngrp - 1; gi >= 0; --gi) {
        const int gb = base + gi * gsz;
        if (gb + gsz <= endi) {
            const int j = gb + t;
            f4 xv[16];
#pragma unroll
            for (int k = 0; k < 16; ++k) xv[k] = x4[j + k * TPB];
            f4 hv[16];
#pragma unroll
            for (int k = 0; k < 16; ++k) {
                const int jj = j + k * TPB;
                hv[k] = hv4[(bi[jj >> 7] << 7) + (jj & 127)];
            }
#pragma unroll
            for (int k = 0; k < 16; ++k) nts(out4 + j + k * TPB, xv[k] + hv[k]);
        } else {
            for (int j = gb + t; j < endi; j += TPB) {
                f4 xv = x4[j];
                int g = bi[j >> 7];
                nts(out4 + j, xv + hv4[(g << 7) + (j & 127)]);
            }
        }
    }
}

extern "C" void kernel_launch(void* const* d_in, const int* in_sizes, int n_in,
                              void* d_out, int out_size, void* d_ws, size_t ws_size,
                              hipStream_t stream) {
    const f4*    x4    = (const f4*)d_in[0];
    const int*   bidx  = (const int*)d_in[1];   // int32 per harness contract
    const float* W1    = (const float*)d_in[2];
    const float* b1    = (const float*)d_in[3];
    const float* W2    = (const float*)d_in[4];
    const float* b2    = (const float*)d_in[5];
    const float* gamma = (const float*)d_in[6];
    const float* beta  = (const float*)d_in[7];

    const int n_nodes = in_sizes[1];
    const size_t x_elems = (size_t)n_nodes * DIM;

    float* out   = (float*)d_out;
    f4*    xnew4 = (f4*)out;                  // output 0: [n_nodes, 512]
    float* hvn   = out + x_elems;             // output 1: [512, 512]

    float* sums = (float*)d_ws;               // 512*512 atomic accumulator

    const int rpb = (n_nodes + NB - 1) / NB;

    hipMemsetAsync(sums, 0, (size_t)NGRAPH * DIM * sizeof(float), stream);
    segsum_kernel<<<NB, TPB, 0, stream>>>(x4, bidx, sums, n_nodes, rpb);
    ffn_kernel<<<64, 512, 0, stream>>>(sums, bidx, W1, b1, W2, b2,
                                       gamma, beta, hvn, n_nodes);
    resid_kernel<<<NB, TPB, 0, stream>>>(x4, bidx, (const f4*)hvn, xnew4,
                                         n_nodes, rpb);
}

// Round 9
// 291.864 us; speedup vs baseline: 1.8189x; 1.8189x over previous
//
#include <hip/hip_runtime.h>

#define DIM 512
#define DIM2 1024
#define NGRAPH 512
#define LN_EPS 1e-5f
#define TPB 256
#define NB 2048   // chunk count for segsum/resid

typedef float f4 __attribute__((ext_vector_type(4)));

__device__ __forceinline__ void nts(f4* p, f4 v) { __builtin_nontemporal_store(v, p); }

// ---------------------------------------------------------------------------
// K1: segment sums, chunk-contiguous, branchless 16-row inner loop (R7).
// ---------------------------------------------------------------------------
__global__ __launch_bounds__(TPB) void segsum_kernel(const f4* __restrict__ x4,
                                                     const int* __restrict__ bi,
                                                     float* __restrict__ sums,
                                                     int n_nodes, int rpb) {
    const int blk = blockIdx.x, t = threadIdx.x;
    const int r0 = blk * rpb;
    const int r1 = min(n_nodes, r0 + rpb);
    if (r0 >= r1) return;
    const int par = t >> 7;      // 256 thr = 2 rows x 128 f4-cols
    const int c = t & 127;

    int cur = r0;
    while (cur < r1) {
        const int g = bi[cur];
        int lo = cur + 1, hi = r1;
        while (lo < hi) {
            int mid = (lo + hi) >> 1;
            if (bi[mid] <= g) lo = mid + 1; else hi = mid;
        }
        const int send = lo;

        f4 a0={0,0,0,0}, a1={0,0,0,0}, a2={0,0,0,0}, a3={0,0,0,0};
        f4 a4={0,0,0,0}, a5={0,0,0,0}, a6={0,0,0,0}, a7={0,0,0,0};
        int r = cur;
        for (; r + 16 <= send; r += 16) {
            const size_t b = (size_t)(r + par) * 128 + c;
            f4 v0 = x4[b];        f4 v1 = x4[b + 256];
            f4 v2 = x4[b + 512];  f4 v3 = x4[b + 768];
            f4 v4 = x4[b + 1024]; f4 v5 = x4[b + 1280];
            f4 v6 = x4[b + 1536]; f4 v7 = x4[b + 1792];
            a0 += v0; a1 += v1; a2 += v2; a3 += v3;
            a4 += v4; a5 += v5; a6 += v6; a7 += v7;
        }
        if (r + 8 <= send) {
            const size_t b = (size_t)(r + par) * 128 + c;
            f4 v0 = x4[b];       f4 v1 = x4[b + 256];
            f4 v2 = x4[b + 512]; f4 v3 = x4[b + 768];
            a0 += v0; a1 += v1; a2 += v2; a3 += v3;
            r += 8;
        }
        for (int rr = r + par; rr < send; rr += 2)
            a0 += x4[(size_t)rr * 128 + c];

        a0 += a1 + a2 + a3 + a4 + a5 + a6 + a7;
        float* d = sums + (size_t)g * DIM + c * 4;
        atomicAdd(d + 0, a0[0]);
        atomicAdd(d + 1, a0[1]);
        atomicAdd(d + 2, a0[2]);
        atomicAdd(d + 3, a0[3]);
        cur = send;
    }
}

// ---------------------------------------------------------------------------
// K2: gemm1 split-K. grid (4 colblk x 64 rowblk x 4 kslice) = 1024 blocks.
// Each thread: 1 col, 8 rows, K-chain 128 (unroll 8 -> 8 W1 loads in
// flight; S row reads are block-uniform -> scalar cache). Mean-fold (inv)
// applied to the partial (linear), fp32 atomicAdd into zeroed h1raw.
// ---------------------------------------------------------------------------
__global__ __launch_bounds__(256) void gemm1_sk_kernel(const float* __restrict__ S,
                                                       const int* __restrict__ bi,
                                                       const float* __restrict__ W1,
                                                       float* __restrict__ h1raw,
                                                       int n_nodes) {
    const int col = blockIdx.x * 256 + threadIdx.x;
    const int r0 = blockIdx.y * 8;
    const int k0 = blockIdx.z * 128;
    __shared__ int sb[9];
    if (threadIdx.x < 9) {
        int v = r0 + (int)threadIdx.x;
        int lo = 0, hi = n_nodes;
        while (lo < hi) {
            int mid = (lo + hi) >> 1;
            if (bi[mid] < v) lo = mid + 1; else hi = mid;
        }
        sb[threadIdx.x] = lo;
    }
    __syncthreads();
    float inv[8];
#pragma unroll
    for (int r = 0; r < 8; ++r) {
        int cnt = sb[r + 1] - sb[r];
        inv[r] = 1.0f / (float)(cnt > 0 ? cnt : 1);
    }
    float acc[8] = {0,0,0,0,0,0,0,0};
#pragma unroll 8
    for (int k = k0; k < k0 + 128; ++k) {
        float w = W1[(size_t)k * DIM2 + col];
#pragma unroll
        for (int r = 0; r < 8; ++r)
            acc[r] += S[(size_t)(r0 + r) * DIM + k] * w;
    }
#pragma unroll
    for (int r = 0; r < 8; ++r)
        atomicAdd(&h1raw[(size_t)(r0 + r) * DIM2 + col], acc[r] * inv[r]);
}

// ---------------------------------------------------------------------------
// K3: h1act = relu(h1raw + b1). Elementwise, f4-vectorized (8 MB total).
// ---------------------------------------------------------------------------
__global__ __launch_bounds__(256) void bias_relu_kernel(const f4* __restrict__ h1raw,
                                                        const float* __restrict__ b1,
                                                        f4* __restrict__ h1act) {
    const int i = blockIdx.x * 256 + threadIdx.x;   // grid covers 512*1024/4
    const f4 bb = *(const f4*)&b1[(i & (DIM2 / 4 - 1)) * 4];
    f4 v = h1raw[i] + bb;
    f4 z = {0,0,0,0};
#pragma unroll
    for (int j = 0; j < 4; ++j) v[j] = v[j] > 0.0f ? v[j] : 0.0f;
    h1act[i] = v + z;
}

// ---------------------------------------------------------------------------
// K4: gemm2 split-K. grid (2 x 64 x 8) = 1024 blocks; K-chain 128,
// unroll 8. h1act row reads block-uniform -> scalar cache. Atomics into
// zeroed h2raw; bias/LN applied in K5.
// ---------------------------------------------------------------------------
__global__ __launch_bounds__(256) void gemm2_sk_kernel(const float* __restrict__ h1act,
                                                       const float* __restrict__ W2,
                                                       float* __restrict__ h2raw) {
    const int col = blockIdx.x * 256 + threadIdx.x;
    const int r0 = blockIdx.y * 8;
    const int k0 = blockIdx.z * 128;
    float acc[8] = {0,0,0,0,0,0,0,0};
#pragma unroll 8
    for (int k = k0; k < k0 + 128; ++k) {
        float w = W2[(size_t)k * DIM + col];
#pragma unroll
        for (int r = 0; r < 8; ++r)
            acc[r] += h1act[(size_t)(r0 + r) * DIM2 + k] * w;
    }
#pragma unroll
    for (int r = 0; r < 8; ++r)
        atomicAdd(&h2raw[(size_t)(r0 + r) * DIM + col], acc[r]);
}

// ---------------------------------------------------------------------------
// K5: LayerNorm of (h2raw + b2) -> hvn (d_out tail). 64 blocks x 512 thr,
// 8 rows per block; shuffle + LDS reduce.
// ---------------------------------------------------------------------------
__global__ __launch_bounds__(512) void ln_kernel(const float* __restrict__ h2raw,
                                                 const float* __restrict__ b2,
                                                 const float* __restrict__ gamma,
                                                 const float* __restrict__ beta,
                                                 float* __restrict__ hvn) {
    const int t = threadIdx.x;
    const int r0 = blockIdx.x * 8;
    float bb = b2[t];
    float v[8];
#pragma unroll
    for (int r = 0; r < 8; ++r) v[r] = h2raw[(size_t)(r0 + r) * DIM + t] + bb;

    __shared__ float sh_s[8][8], sh_ss[8][8];
    const int wid = t >> 6, lane = t & 63;
#pragma unroll
    for (int r = 0; r < 8; ++r) {
        float s = v[r], ss = v[r] * v[r];
#pragma unroll
        for (int off = 32; off > 0; off >>= 1) {
            s  += __shfl_xor(s,  off);
            ss += __shfl_xor(ss, off);
        }
        if (lane == 0) { sh_s[r][wid] = s; sh_ss[r][wid] = ss; }
    }
    __syncthreads();
    float gm = gamma[t], bt = beta[t];
#pragma unroll
    for (int r = 0; r < 8; ++r) {
        float s = 0.f, ss = 0.f;
#pragma unroll
        for (int w = 0; w < 8; ++w) { s += sh_s[r][w]; ss += sh_ss[r][w]; }
        float mu  = s * (1.0f / DIM);
        float var = ss * (1.0f / DIM) - mu * mu;
        float rs  = rsqrtf(var + LN_EPS);
        hvn[(size_t)(r0 + r) * DIM + t] = (v[r] - mu) * rs * gm + bt;
    }
}

// ---------------------------------------------------------------------------
// K6: x_new = x + hvn[batch_idx] (R7). Reverse macro-order, 16 loads in
// flight per lane, NT stores.
// ---------------------------------------------------------------------------
__global__ __launch_bounds__(TPB) void resid_kernel(const f4* __restrict__ x4,
                                                    const int* __restrict__ bi,
                                                    const f4* __restrict__ hv4,
                                                    f4* __restrict__ out4,
                                                    int n_nodes, int rpb) {
    const int blk = blockIdx.x, t = threadIdx.x;
    const int r0 = blk * rpb;
    const int r1 = min(n_nodes, r0 + rpb);
    if (r0 >= r1) return;
    const int base = r0 * 128, endi = r1 * 128;
    const int gsz = TPB * 16;
    const int ngrp = (endi - base + gsz - 1) / gsz;

    for (int gi = ngrp - 1; gi >= 0; --gi) {
        const int gb = base + gi * gsz;
        if (gb + gsz <= endi) {
            const int j = gb + t;
            f4 xv[16];
#pragma unroll
            for (int k = 0; k < 16; ++k) xv[k] = x4[j + k * TPB];
            f4 hv[16];
#pragma unroll
            for (int k = 0; k < 16; ++k) {
                const int jj = j + k * TPB;
                hv[k] = hv4[(bi[jj >> 7] << 7) + (jj & 127)];
            }
#pragma unroll
            for (int k = 0; k < 16; ++k) nts(out4 + j + k * TPB, xv[k] + hv[k]);
        } else {
            for (int j = gb + t; j < endi; j += TPB) {
                f4 xv = x4[j];
                int g = bi[j >> 7];
                nts(out4 + j, xv + hv4[(g << 7) + (j & 127)]);
            }
        }
    }
}

extern "C" void kernel_launch(void* const* d_in, const int* in_sizes, int n_in,
                              void* d_out, int out_size, void* d_ws, size_t ws_size,
                              hipStream_t stream) {
    const f4*    x4    = (const f4*)d_in[0];
    const int*   bidx  = (const int*)d_in[1];   // int32 per harness contract
    const float* W1    = (const float*)d_in[2];
    const float* b1    = (const float*)d_in[3];
    const float* W2    = (const float*)d_in[4];
    const float* b2    = (const float*)d_in[5];
    const float* gamma = (const float*)d_in[6];
    const float* beta  = (const float*)d_in[7];

    const int n_nodes = in_sizes[1];
    const size_t x_elems = (size_t)n_nodes * DIM;

    float* out   = (float*)d_out;
    f4*    xnew4 = (f4*)out;                  // output 0: [n_nodes, 512]
    float* hvn   = out + x_elems;             // output 1: [512, 512]

    // workspace: sums(1MB) | h1raw(4MB) | h2raw(1MB) | h1act(4MB)
    float* sums  = (float*)d_ws;
    float* h1raw = sums  + (size_t)NGRAPH * DIM;
    float* h2raw = h1raw + (size_t)NGRAPH * DIM2;
    float* h1act = h2raw + (size_t)NGRAPH * DIM;

    const int rpb = (n_nodes + NB - 1) / NB;

    // zero all atomic accumulators in one shot (sums+h1raw+h2raw = 6 MB)
    hipMemsetAsync(sums, 0,
                   (size_t)(NGRAPH * DIM + NGRAPH * DIM2 + NGRAPH * DIM) * sizeof(float),
                   stream);
    segsum_kernel<<<NB, TPB, 0, stream>>>(x4, bidx, sums, n_nodes, rpb);
    gemm1_sk_kernel<<<dim3(4, 64, 4), 256, 0, stream>>>(sums, bidx, W1, h1raw, n_nodes);
    bias_relu_kernel<<<(NGRAPH * DIM2 / 4) / 256, 256, 0, stream>>>((const f4*)h1raw,
                                                                    b1, (f4*)h1act);
    gemm2_sk_kernel<<<dim3(2, 64, 8), 256, 0, stream>>>(h1act, W2, h2raw);
    ln_kernel<<<64, 512, 0, stream>>>(h2raw, b2, gamma, beta, hvn);
    resid_kernel<<<NB, TPB, 0, stream>>>(x4, bidx, (const f4*)hvn, xnew4,
                                         n_nodes, rpb);
}